// Round 9
// baseline (145.868 us; speedup 1.0000x reference)
//
#include <hip/hip_runtime.h>

typedef __attribute__((ext_vector_type(8))) short s16x8;
typedef __attribute__((ext_vector_type(8))) ushort u16x8;
typedef __attribute__((ext_vector_type(4))) ushort u16x4;
typedef __attribute__((ext_vector_type(4))) float f32x4v;

namespace {

constexpr int kB = 2;
constexpr int kN = 16384;
constexpr int kC = 256;
constexpr int kQR = 1024;  // q rows per batch that reach the output

__device__ __forceinline__ ushort f2bf(float f) {
  union { float f; uint u; } v; v.f = f;
  uint u = v.u + 0x7fffu + ((v.u >> 16) & 1u);
  return (ushort)(u >> 16);
}

__device__ __forceinline__ float phi_act(float x) {
  // elu(elu(x)+1)+1 == x>0 ? x+2 : exp(x)+1
  return x > 0.f ? x + 2.f : __expf(x) + 1.f;
}

// ---- 1. weight transpose+convert: W[k][j] f32 -> WT[j][k] bf16
__global__ __launch_bounds__(256) void wt_kernel(const float* __restrict__ Wq,
                                                 const float* __restrict__ Wk,
                                                 ushort* __restrict__ WqT,
                                                 ushort* __restrict__ WkT) {
  __shared__ float ts[64][65];
  const float* W = blockIdx.z ? Wk : Wq;
  ushort* WT = blockIdx.z ? WkT : WqT;
  const int bi = blockIdx.x, bj = blockIdx.y, t = threadIdx.x;
  for (int rep = 0; rep < 16; ++rep) {
    int e = rep * 256 + t, r = e >> 6, c = e & 63;
    ts[r][c] = W[(size_t)(bi * 64 + r) * kC + bj * 64 + c];
  }
  __syncthreads();
  for (int rep = 0; rep < 16; ++rep) {
    int e = rep * 256 + t, j = e >> 6, k = e & 63;
    WT[(size_t)(bj * 64 + j) * kC + bi * 64 + k] = f2bf(ts[k][j]);
  }
}

// ---- 2. regroup: input f32 [b][n][256] -> bf16 grouped [b][m][wgrp(128)][c(256)][8w]
__global__ __launch_bounds__(256) void regroup_kernel(const float* __restrict__ X,
                                                      ushort* __restrict__ G) {
  __shared__ ushort ls[64 * 288];  // [w(64)][m stride 18][c(16)]
  const int cb = blockIdx.x;   // 16 c-blocks of 16
  const int wb = blockIdx.y;   // 16 w-blocks of 64 windows (1024 rows)
  const int b = blockIdx.z;
  const int t = threadIdx.x;
  const float* src = X + ((size_t)b * kN + wb * 1024) * kC + cb * 16;
  const int lr = t >> 2, cg = t & 3;
  for (int rep = 0; rep < 16; ++rep) {
    int row = rep * 64 + lr;  // 0..1023
    float4 v = *reinterpret_cast<const float4*>(src + (size_t)row * kC + cg * 4);
    int w = row >> 4, m = row & 15;
    int base = w * 288 + m * 18 + cg * 4;
    uint p0 = (uint)f2bf(v.x) | ((uint)f2bf(v.y) << 16);
    uint p1 = (uint)f2bf(v.z) | ((uint)f2bf(v.w) << 16);
    *reinterpret_cast<uint*>(ls + base) = p0;
    *reinterpret_cast<uint*>(ls + base + 2) = p1;
  }
  __syncthreads();
  const int m = t >> 4, c_l = t & 15;
  const size_t gbase = ((size_t)b * 16 + m) * 128 + wb * 8;
#pragma unroll
  for (int r = 0; r < 8; ++r) {
    u16x8 v;
#pragma unroll
    for (int wl = 0; wl < 8; ++wl) v[wl] = ls[(r * 8 + wl) * 288 + m * 18 + c_l];
    *reinterpret_cast<u16x8*>(G + (gbase + r) * 2048 + (size_t)(cb * 16 + c_l) * 8) = v;
  }
}

// ---- 3. fused projections.
// blocks 0..255: K-mode: phi_k -> kg (grouped [bm][wgrp][c][8w]).
// blocks 256..271: Q-mode: phi_q -> qf flat [row][c].
__global__ __launch_bounds__(512) void proj_fused(
    const float* __restrict__ X, const ushort* __restrict__ WqT,
    const ushort* __restrict__ WkT, const float* __restrict__ bq,
    const float* __restrict__ bk, ushort* __restrict__ kg,
    ushort* __restrict__ qf) {
  __shared__ __align__(16) ushort smem[24576];  // 48 KB: A dbuf 2x8KB, B dbuf 2x16KB

  const int t = threadIdx.x, lane = t & 63, wv = t >> 6;
  const int bx = blockIdx.x;
  const bool kmode = bx < 256;
  int b, n0;
  const ushort* WT;
  const float* bias;
  if (kmode) {
    b = bx >> 7; n0 = (bx & 127) * 128; WT = WkT; bias = bk;
  } else {
    int i = bx - 256; b = i >> 3; n0 = (i & 7) * 128; WT = WqT; bias = bq;
  }
  const int wgrp = bx & 127;  // valid in kmode only
  const float* Xbase = X + ((size_t)b * kN + n0) * kC;

  // A-stage: thread owns (row r4, cols ca..ca+7): 2 float4 -> 1 ds_write_b128
  const int r4 = t >> 2, ca = (t & 3) << 3;
  // B-stage: thread owns rows bj, bj+128 at chunk bch
  const int bj = t >> 2, bch = t & 3;

  float4 fa0, fa1;
  u16x8 rb0, rb1;
  auto stageLoad = [&](int ks) {
    const int k0 = ks * 32;
    fa0 = *reinterpret_cast<const float4*>(Xbase + (size_t)r4 * kC + k0 + ca);
    fa1 = *reinterpret_cast<const float4*>(Xbase + (size_t)r4 * kC + k0 + ca + 4);
    rb0 = *reinterpret_cast<const u16x8*>(WT + (size_t)bj * kC + k0 + bch * 8);
    rb1 = *reinterpret_cast<const u16x8*>(WT + (size_t)(bj + 128) * kC + k0 + bch * 8);
  };
  auto stageWrite = [&](int h) {
    ushort* A = smem + h * 4096;
    ushort* B = smem + 8192 + h * 8192;
    u16x8 va;
    va[0] = f2bf(fa0.x); va[1] = f2bf(fa0.y); va[2] = f2bf(fa0.z); va[3] = f2bf(fa0.w);
    va[4] = f2bf(fa1.x); va[5] = f2bf(fa1.y); va[6] = f2bf(fa1.z); va[7] = f2bf(fa1.w);
    *reinterpret_cast<u16x8*>(A + r4 * 32 + (((t & 3) ^ ((r4 >> 1) & 3)) << 3)) = va;
    *reinterpret_cast<u16x8*>(B + bj * 32 + ((bch ^ ((bj >> 1) & 3)) << 3)) = rb0;
    *reinterpret_cast<u16x8*>(B + (bj + 128) * 32 + ((bch ^ (((bj + 128) >> 1) & 3)) << 3)) = rb1;
  };

  f32x4v acc[4][4] = {};
  const int lo = lane & 15, hi = lane >> 4;
  const int wr0 = (wv >> 2) * 64, wc0 = (wv & 3) * 64;
  auto mma = [&](int h) {
    const ushort* A = smem + h * 4096;
    const ushort* B = smem + 8192 + h * 8192;
    s16x8 af[4], bf[4];
#pragma unroll
    for (int i = 0; i < 4; ++i) {
      int r = wr0 + i * 16 + lo;
      af[i] = *reinterpret_cast<const s16x8*>(A + r * 32 + ((hi ^ ((r >> 1) & 3)) << 3));
    }
#pragma unroll
    for (int j = 0; j < 4; ++j) {
      int cj = wc0 + j * 16 + lo;
      bf[j] = *reinterpret_cast<const s16x8*>(B + cj * 32 + ((hi ^ ((cj >> 1) & 3)) << 3));
    }
#pragma unroll
    for (int i = 0; i < 4; ++i)
#pragma unroll
      for (int j = 0; j < 4; ++j)
        acc[i][j] = __builtin_amdgcn_mfma_f32_16x16x32_bf16(af[i], bf[j], acc[i][j], 0, 0, 0);
  };

  stageLoad(0);
  stageWrite(0);
  __syncthreads();
  int cur = 0;
  for (int ks = 0; ks < 8; ++ks) {
    if (ks < 7) stageLoad(ks + 1);
    __builtin_amdgcn_sched_barrier(0);
    mma(cur);
    __builtin_amdgcn_sched_barrier(0);
    if (ks < 7) stageWrite(cur ^ 1);
    __syncthreads();
    cur ^= 1;
  }

  float bv[4];
#pragma unroll
  for (int fj = 0; fj < 4; ++fj) bv[fj] = bias[wc0 + fj * 16 + lo];

  if (kmode) {
    // two-half LDS transpose epilogue -> grouped kg, one u16x8 store per (m,c)
    const int m = t >> 5, cl = t & 31;
    u16x8 vout[8];
    ushort* ep = smem;  // [64][260]
#pragma unroll
    for (int h = 0; h < 2; ++h) {
      __syncthreads();
      if ((wv >> 2) == h) {
#pragma unroll
        for (int fi = 0; fi < 4; ++fi)
#pragma unroll
          for (int fj = 0; fj < 4; ++fj)
#pragma unroll
            for (int r = 0; r < 4; ++r) {
              int rl = fi * 16 + hi * 4 + r;
              int col = wc0 + fj * 16 + lo;
              ep[rl * 260 + col] = f2bf(phi_act(acc[fi][fj][r] + bv[fj]));
            }
      }
      __syncthreads();
#pragma unroll
      for (int j = 0; j < 8; ++j) {
        int c = j * 32 + cl;
#pragma unroll
        for (int wl = 0; wl < 4; ++wl)
          vout[j][h * 4 + wl] = ep[(wl * 16 + m) * 260 + c];
      }
    }
#pragma unroll
    for (int j = 0; j < 8; ++j) {
      int c = j * 32 + cl;
      *reinterpret_cast<u16x8*>(
          kg + (((size_t)(b * 16 + m) * 128 + wgrp) * 256 + c) * 8) = vout[j];
    }
  } else {
#pragma unroll
    for (int fi = 0; fi < 4; ++fi)
#pragma unroll
      for (int fj = 0; fj < 4; ++fj)
#pragma unroll
        for (int r = 0; r < 4; ++r) {
          int row = n0 + wr0 + fi * 16 + hi * 4 + r;
          int col = wc0 + fj * 16 + lo;
          qf[((size_t)b * kQR + row) * kC + col] = f2bf(phi_act(acc[fi][fj][r] + bv[fj]));
        }
  }
}

// ---- 4. KV GEMM per (b,m): KVT[d][c] = sum_w kg[c][w] * xg[d][w], K=1024
// tile 64x64, 1D grid 512 with bijective XCD swizzle, BK=64, double-buffered.
__global__ __launch_bounds__(256) void kv_kernel(const ushort* __restrict__ kg,
                                                 const ushort* __restrict__ xg,
                                                 ushort* __restrict__ kvt) {
  __shared__ __align__(16) ushort smem[16384];  // 32 KB
  const int t = threadIdx.x, lane = t & 63, wv = t >> 6;
  // bijective XCD swizzle: 512 blocks, 8 XCDs, 64 per XCD; 16 blocks (one bm)
  // stay contiguous on one XCD -> kg/xg panels become L2-resident.
  const int swz = (blockIdx.x & 7) * 64 + (blockIdx.x >> 3);
  const int bm = swz >> 4, cb = swz & 3, db = (swz >> 2) & 3;
  const int lc = t & 63, g2 = t >> 6;  // staging: row lc, chunks g2 & g2+4

  u16x8 ra0, ra1, rb0, rb1;
  auto stageLoad = [&](int ws) {
    size_t base = (size_t)bm * 128 + ws * 8;
    ra0 = *reinterpret_cast<const u16x8*>(kg + ((base + g2) * 256 + cb * 64 + lc) * 8);
    ra1 = *reinterpret_cast<const u16x8*>(kg + ((base + g2 + 4) * 256 + cb * 64 + lc) * 8);
    rb0 = *reinterpret_cast<const u16x8*>(xg + ((base + g2) * 256 + db * 64 + lc) * 8);
    rb1 = *reinterpret_cast<const u16x8*>(xg + ((base + g2 + 4) * 256 + db * 64 + lc) * 8);
  };
  auto stageWrite = [&](int h) {
    ushort* A = smem + h * 4096;
    ushort* B = smem + 8192 + h * 4096;
    int s = (lc >> 1) & 7;
    *reinterpret_cast<u16x8*>(A + lc * 64 + ((g2 ^ s) << 3)) = ra0;
    *reinterpret_cast<u16x8*>(A + lc * 64 + (((g2 + 4) ^ s) << 3)) = ra1;
    *reinterpret_cast<u16x8*>(B + lc * 64 + ((g2 ^ s) << 3)) = rb0;
    *reinterpret_cast<u16x8*>(B + lc * 64 + (((g2 + 4) ^ s) << 3)) = rb1;
  };

  f32x4v acc[2][2] = {};
  const int lo = lane & 15, hi = lane >> 4;
  const int wr0 = (wv >> 1) * 32, wc0 = (wv & 1) * 32;
  auto mma = [&](int h) {
    const ushort* A = smem + h * 4096;
    const ushort* B = smem + 8192 + h * 4096;
    s16x8 af[2][2], bf[2][2];
#pragma unroll
    for (int i = 0; i < 2; ++i) {
      int r = wr0 + i * 16 + lo;
      int s = (r >> 1) & 7;
#pragma unroll
      for (int kk = 0; kk < 2; ++kk)
        af[i][kk] = *reinterpret_cast<const s16x8*>(A + r * 64 + (((kk * 4 + hi) ^ s) << 3));
    }
#pragma unroll
    for (int j = 0; j < 2; ++j) {
      int c = wc0 + j * 16 + lo;
      int s = (c >> 1) & 7;
#pragma unroll
      for (int kk = 0; kk < 2; ++kk)
        bf[j][kk] = *reinterpret_cast<const s16x8*>(B + c * 64 + (((kk * 4 + hi) ^ s) << 3));
    }
#pragma unroll
    for (int kk = 0; kk < 2; ++kk)
#pragma unroll
      for (int i = 0; i < 2; ++i)
#pragma unroll
        for (int j = 0; j < 2; ++j)
          acc[i][j] = __builtin_amdgcn_mfma_f32_16x16x32_bf16(af[i][kk], bf[j][kk], acc[i][j], 0, 0, 0);
  };

  stageLoad(0);
  stageWrite(0);
  __syncthreads();
  int cur = 0;
  for (int ws = 0; ws < 16; ++ws) {
    if (ws < 15) stageLoad(ws + 1);
    __builtin_amdgcn_sched_barrier(0);
    mma(cur);
    __builtin_amdgcn_sched_barrier(0);
    if (ws < 15) stageWrite(cur ^ 1);
    __syncthreads();
    cur ^= 1;
  }
#pragma unroll
  for (int i = 0; i < 2; ++i)
#pragma unroll
    for (int j = 0; j < 2; ++j) {
      int d = db * 64 + wc0 + j * 16 + lo;
      int c = cb * 64 + wr0 + i * 16 + hi * 4;
      u16x4 v = {f2bf(acc[i][j][0]), f2bf(acc[i][j][1]), f2bf(acc[i][j][2]),
                 f2bf(acc[i][j][3])};
      *reinterpret_cast<u16x4*>(kvt + ((size_t)bm * 256 + d) * 256 + c) = v;
    }
}

// ---- 5. out GEMM per (b,m): Out[qr*16+m][d] = qf[qr] . kvt[d] + p
__global__ __launch_bounds__(256) void out_kernel(
    const ushort* __restrict__ qf, const ushort* __restrict__ kvt,
    const float* __restrict__ EQK, const float* __restrict__ Wp,
    const float* __restrict__ bp, float* __restrict__ Out) {
  __shared__ __align__(16) ushort smem[16384];  // 32 KB
  __shared__ float Ps[128];
  const int t = threadIdx.x, lane = t & 63, wv = t >> 6;
  // bijective XCD swizzle, 512 blocks: one bm's 16 blocks share an XCD.
  const int swz = (blockIdx.x & 7) * 64 + (blockIdx.x >> 3);
  const int bm = swz >> 4, qb = swz & 7, db = (swz >> 3) & 1;
  const int b = bm >> 4, mm = bm & 15;
  if (t < 128) {
    int qr = qb * 128 + t;
    const float* e = EQK + (((size_t)(b * 1024 + (qr >> 4)) * 16 + (qr & 15)) * 16 + mm) * 3;
    Ps[t] = e[0] * Wp[0] + e[1] * Wp[1] + e[2] * Wp[2] + bp[0];
  }
  const int r2 = t >> 2, ch = t & 3;  // staging rows r2, r2+64 at chunk ch

  u16x8 ra0, ra1, rb0, rb1;
  auto stageLoad = [&](int ks) {
    int k0 = ks * 32;
    const ushort* Aq = qf + ((size_t)b * kQR + qb * 128) * kC;
    const ushort* Bk = kvt + ((size_t)bm * 256 + db * 128) * kC;
    ra0 = *reinterpret_cast<const u16x8*>(Aq + (size_t)r2 * kC + k0 + ch * 8);
    ra1 = *reinterpret_cast<const u16x8*>(Aq + (size_t)(r2 + 64) * kC + k0 + ch * 8);
    rb0 = *reinterpret_cast<const u16x8*>(Bk + (size_t)r2 * kC + k0 + ch * 8);
    rb1 = *reinterpret_cast<const u16x8*>(Bk + (size_t)(r2 + 64) * kC + k0 + ch * 8);
  };
  auto stageWrite = [&](int h) {
    ushort* A = smem + h * 4096;
    ushort* B = smem + 8192 + h * 4096;
    *reinterpret_cast<u16x8*>(A + r2 * 32 + ((ch ^ ((r2 >> 1) & 3)) << 3)) = ra0;
    *reinterpret_cast<u16x8*>(A + (r2 + 64) * 32 + ((ch ^ (((r2 + 64) >> 1) & 3)) << 3)) = ra1;
    *reinterpret_cast<u16x8*>(B + r2 * 32 + ((ch ^ ((r2 >> 1) & 3)) << 3)) = rb0;
    *reinterpret_cast<u16x8*>(B + (r2 + 64) * 32 + ((ch ^ (((r2 + 64) >> 1) & 3)) << 3)) = rb1;
  };

  f32x4v acc[4][4] = {};
  const int lo = lane & 15, hi = lane >> 4;
  const int wr0 = (wv >> 1) * 64, wc0 = (wv & 1) * 64;
  auto mma = [&](int h) {
    const ushort* A = smem + h * 4096;
    const ushort* B = smem + 8192 + h * 4096;
    s16x8 af[4], bf[4];
#pragma unroll
    for (int i = 0; i < 4; ++i) {
      int r = wr0 + i * 16 + lo;
      af[i] = *reinterpret_cast<const s16x8*>(A + r * 32 + ((hi ^ ((r >> 1) & 3)) << 3));
    }
#pragma unroll
    for (int j = 0; j < 4; ++j) {
      int c = wc0 + j * 16 + lo;
      bf[j] = *reinterpret_cast<const s16x8*>(B + c * 32 + ((hi ^ ((c >> 1) & 3)) << 3));
    }
#pragma unroll
    for (int i = 0; i < 4; ++i)
#pragma unroll
      for (int j = 0; j < 4; ++j)
        acc[i][j] = __builtin_amdgcn_mfma_f32_16x16x32_bf16(af[i], bf[j], acc[i][j], 0, 0, 0);
  };

  stageLoad(0);
  stageWrite(0);
  __syncthreads();
  int cur = 0;
  for (int ks = 0; ks < 8; ++ks) {
    if (ks < 7) stageLoad(ks + 1);
    __builtin_amdgcn_sched_barrier(0);
    mma(cur);
    __builtin_amdgcn_sched_barrier(0);
    if (ks < 7) stageWrite(cur ^ 1);
    __syncthreads();
    cur ^= 1;
  }
#pragma unroll
  for (int fi = 0; fi < 4; ++fi)
#pragma unroll
    for (int r4 = 0; r4 < 4; ++r4) {
      int rowl = wr0 + fi * 16 + hi * 4 + r4;
      int qr = qb * 128 + rowl;
      float p = Ps[rowl];
      size_t orow = ((size_t)b * kN + (size_t)qr * 16 + mm) * kC;
#pragma unroll
      for (int fj = 0; fj < 4; ++fj) {
        int d = db * 128 + wc0 + fj * 16 + lo;
        Out[orow + d] = acc[fi][fj][r4] + p;
      }
    }
}

}  // namespace

extern "C" void kernel_launch(void* const* d_in, const int* in_sizes, int n_in,
                              void* d_out, int out_size, void* d_ws,
                              size_t ws_size, hipStream_t stream) {
  const float* input = (const float*)d_in[0];
  const float* eqk = (const float*)d_in[1];
  const float* Wq = (const float*)d_in[2];
  const float* bq = (const float*)d_in[3];
  const float* Wk = (const float*)d_in[4];
  const float* bk = (const float*)d_in[5];
  const float* Wp = (const float*)d_in[6];
  const float* bp = (const float*)d_in[7];
  float* out = (float*)d_out;

  ushort* ws = (ushort*)d_ws;
  ushort* WqT = ws;                  // 65536
  ushort* WkT = WqT + 65536;         // 65536
  ushort* xg = WkT + 65536;          // 8388608  grouped v  [bm][wgrp][c][8]
  ushort* kg = xg + 8388608;         // 8388608  grouped phi_k
  ushort* qf = kg + 8388608;         // 524288   phi_q flat [2048][256]
  ushort* kvt = qf + 524288;         // 2097152  KVT [bm][d][c]

  wt_kernel<<<dim3(4, 4, 2), 256, 0, stream>>>(Wq, Wk, WqT, WkT);
  regroup_kernel<<<dim3(16, 16, 2), 256, 0, stream>>>(input, xg);
  proj_fused<<<dim3(272), 512, 0, stream>>>(input, WqT, WkT, bq, bk, kg, qf);
  kv_kernel<<<dim3(512), 256, 0, stream>>>(kg, xg, kvt);
  out_kernel<<<dim3(512), 256, 0, stream>>>(qf, kvt, eqk, Wp, bp, out);
}